// Round 5
// baseline (172.467 us; speedup 1.0000x reference)
//
#include <hip/hip_runtime.h>
#include <math.h>

#define BATCH 4
#define CH    256   // feature channels == depth of sampled volume
#define HH    128
#define WW    128
#define PC    256   // para channels
#define PI_F  3.14159f
#define PLANE (HH * WW)   // 16384 floats = 64 KiB
#define NP    4           // planes per sampler block

// ---------------------------------------------------------------------------
// Kernel 1: all affine params in one tiny launch (grid=4, one block/batch).
// Phase A: p = relu(pc @ W1 + b1), 4-way k-split over 1024 threads.
// Phase B: 4 head dots per channel (thread = (head,channel)), then
//          transcendentals -> fused pixel-space constants
//          ix = cA*x - cB*y + C0 ; iy = cB*x + cA*y + C1.
// ---------------------------------------------------------------------------
__global__ __launch_bounds__(1024)
void adaat_params_kernel(const float* __restrict__ pc,
                         const float* __restrict__ W1, const float* __restrict__ b1,
                         const float* __restrict__ Ws, const float* __restrict__ bs,
                         const float* __restrict__ Wr, const float* __restrict__ br,
                         const float* __restrict__ Wt, const float* __restrict__ bt,
                         float4* __restrict__ params) {
    __shared__ float red[1024];
    __shared__ float p_sh[PC];
    __shared__ float hd[4][PC];
    const int b = blockIdx.x;
    const int t = threadIdx.x;

    {   // A: GEMV
        const int jj = t & 255, kk = t >> 8;
        const float* pcb = pc + b * PC + kk * 64;
        const float* w   = W1 + (kk * 64) * PC + jj;
        float acc = 0.0f;
#pragma unroll 8
        for (int i = 0; i < 64; ++i)
            acc = fmaf(pcb[i], w[i * PC], acc);
        red[t] = acc;
    }
    __syncthreads();
    if (t < 256)
        p_sh[t] = fmaxf(red[t] + red[256 + t] + red[512 + t] + red[768 + t] + b1[t], 0.0f);
    __syncthreads();

    {   // B: heads
        const int c = t & 255, h = t >> 8;
        const float* wp; int stride;
        if      (h == 0) { wp = Ws + c;               stride = PC;     }
        else if (h == 1) { wp = Wr + c;               stride = PC;     }
        else             { wp = Wt + 2 * c + (h == 3); stride = 2 * PC; }
        float dot = 0.0f;
#pragma unroll 8
        for (int k = 0; k < PC; ++k)
            dot = fmaf(p_sh[k], wp[(size_t)k * stride], dot);
        hd[h][c] = dot;
    }
    __syncthreads();
    if (t < 256) {
        const int c = t;
        const float s   = 2.0f / (1.0f + expf(-(hd[0][c] + bs[c])));
        const float ang = tanhf(hd[1][c] + br[c]) * PI_F;
        float sa, ca;
        sincosf(ang, &sa, &ca);
        const float A  = s * ca, B = s * sa;
        const float Tx = tanhf(hd[2][c] + bt[2 * c]);
        const float Ty = tanhf(hd[3][c] + bt[2 * c + 1]);
        params[b * CH + c] = make_float4(A * (128.0f / 127.0f),
                                         B * (128.0f / 127.0f),
                                         64.0f * (Tx - A + B) + 63.5f,
                                         64.0f * (Ty - A - B) + 63.5f);
    }
}

// ---------------------------------------------------------------------------
// Sampler: 256 blocks x 1024 threads, NP=4 planes/block, double-buffered LDS.
// Pipeline per plane i:  load(i+1) -> gather(i) -> combine/store(i+1) -> barrier
// The plane-(i+1) global loads are issued at the TOP of the post-barrier
// region so no load is ever in flight across a __syncthreads (which drains
// vmcnt); their latency hides behind gather(i)'s VALU+LDS work.
// ---------------------------------------------------------------------------
struct Stage { float4 a[4]; float4 b[4]; };

__device__ __forceinline__ Stage stage_load(const float* __restrict__ pl0,
                                            const float* __restrict__ pl1, int t) {
    Stage s;
#pragma unroll
    for (int j = 0; j < 4; ++j) {
        const int f = 4 * (t + 1024 * j);
        s.a[j] = *(const float4*)(pl0 + f);
        s.b[j] = *(const float4*)(pl1 + f);
    }
    return s;
}

__device__ __forceinline__ void stage_store(float* __restrict__ buf, const Stage& s,
                                            float wz0, float wz1, int t) {
#pragma unroll
    for (int j = 0; j < 4; ++j) {
        const int f = 4 * (t + 1024 * j);
        const int y = f >> 7, x = f & (WW - 1);
        float4 c;
        c.x = fmaf(wz0, s.a[j].x, wz1 * s.b[j].x);
        c.y = fmaf(wz0, s.a[j].y, wz1 * s.b[j].y);
        c.z = fmaf(wz0, s.a[j].z, wz1 * s.b[j].z);
        c.w = fmaf(wz0, s.a[j].w, wz1 * s.b[j].w);
        *(float4*)&buf[y * WW + (x ^ ((y & 3) << 3))] = c;
    }
}

__device__ __forceinline__ void gather_plane(const float* __restrict__ buf,
                                             const float4 P,
                                             float* __restrict__ outp,
                                             const float yf, const int xi) {
    const float cA = P.x, cB = P.y, C0 = P.z, C1 = P.w;
#pragma unroll 2
    for (int k = 0; k < 16; ++k) {
        const float xf  = (float)(k * 8 + xi);
        const float ixf = fmaf(cA, xf, fmaf(-cB, yf, C0));
        const float iyf = fmaf(cB, xf, fmaf(cA, yf, C1));
        const float x0f = floorf(ixf);
        const float y0f = floorf(iyf);
        const float fx  = ixf - x0f;
        const float fy  = iyf - y0f;
        const float mx0 = (x0f >= 0.0f  && x0f < 128.0f) ? (1.0f - fx) : 0.0f;
        const float mx1 = (x0f >= -1.0f && x0f < 127.0f) ? fx          : 0.0f;
        const float my0 = (y0f >= 0.0f  && y0f < 128.0f) ? (1.0f - fy) : 0.0f;
        const float my1 = (y0f >= -1.0f && y0f < 127.0f) ? fy          : 0.0f;

        const int x0i = (int)x0f, y0i = (int)y0f;
        const int xc0 = min(max(x0i,     0), WW - 1);
        const int xc1 = min(max(x0i + 1, 0), WW - 1);
        const int yc0 = min(max(y0i,     0), HH - 1);
        const int yc1 = min(max(y0i + 1, 0), HH - 1);

        const int r0 = yc0 * WW, r1 = yc1 * WW;
        const int s0 = (yc0 & 3) << 3, s1 = (yc1 & 3) << 3;
        const float v00 = buf[r0 + (xc0 ^ s0)];
        const float v01 = buf[r0 + (xc1 ^ s0)];
        const float v10 = buf[r1 + (xc0 ^ s1)];
        const float v11 = buf[r1 + (xc1 ^ s1)];

        outp[k * 8 + xi] = my0 * (mx0 * v00 + mx1 * v01)
                         + my1 * (mx0 * v10 + mx1 * v11);
    }
}

__global__ __launch_bounds__(1024, 4)
void adaat_sample_kernel(const float* __restrict__ fm,
                         const float4* __restrict__ params,
                         float* __restrict__ out) {
    __shared__ float buf[2][PLANE];   // 128 KiB double buffer

    const int t   = threadIdx.x;
    const int bc0 = blockIdx.x * NP;  // NP | 256 so no batch straddle
    const int b   = bc0 >> 8;
    const int wv  = t >> 6, l = t & 63;
    const int xi  = l & 7;
    const int yj  = wv * 8 + (l >> 3);
    const float yf = (float)yj;

    const float* base = fm + (size_t)b * (CH * PLANE);

    // block-uniform staging constants (SGPRs after scalarization)
    const float* pl0[NP]; const float* pl1[NP];
    float w0[NP], w1[NP];
#pragma unroll
    for (int i = 0; i < NP; ++i) {
        const int   c   = (bc0 + i) & (CH - 1);
        const float iz  = (256.0f / 255.0f) * (float)c - 0.5f;
        const float zf  = floorf(iz);
        const float fz  = iz - zf;
        const int   z0  = (int)zf;
        w0[i]  = (z0 >= 0)     ? (1.0f - fz) : 0.0f;
        w1[i]  = (z0 + 1 < CH) ? fz          : 0.0f;
        pl0[i] = base + (size_t)max(z0, 0)          * PLANE;
        pl1[i] = base + (size_t)min(z0 + 1, CH - 1) * PLANE;
    }
    float4 Ps[NP];
#pragma unroll
    for (int i = 0; i < NP; ++i) Ps[i] = params[bc0 + i];

    // prologue: stage plane 0
    Stage s = stage_load(pl0[0], pl1[0], t);
    stage_store(&buf[0][0], s, w0[0], w1[0], t);
    __syncthreads();

    // steady state
#pragma unroll
    for (int i = 1; i < NP; ++i) {
        s = stage_load(pl0[i], pl1[i], t);          // in flight during gather
        gather_plane(&buf[(i - 1) & 1][0], Ps[i - 1],
                     out + (size_t)(bc0 + i - 1) * PLANE + yj * WW, yf, xi);
        stage_store(&buf[i & 1][0], s, w0[i], w1[i], t);
        __syncthreads();
    }

    // epilogue: last gather
    gather_plane(&buf[(NP - 1) & 1][0], Ps[NP - 1],
                 out + (size_t)(bc0 + NP - 1) * PLANE + yj * WW, yf, xi);
}

// ---------------------------------------------------------------------------
extern "C" void kernel_launch(void* const* d_in, const int* in_sizes, int n_in,
                              void* d_out, int out_size, void* d_ws, size_t ws_size,
                              hipStream_t stream) {
    const float* feature_map = (const float*)d_in[0];  // [4,256,128,128]
    const float* para_code   = (const float*)d_in[1];  // [4,256]
    const float* W1 = (const float*)d_in[2];
    const float* b1 = (const float*)d_in[3];
    const float* Ws = (const float*)d_in[4];
    const float* bs = (const float*)d_in[5];
    const float* Wr = (const float*)d_in[6];
    const float* br = (const float*)d_in[7];
    const float* Wt = (const float*)d_in[8];
    const float* bt = (const float*)d_in[9];

    float4* params = (float4*)d_ws;   // 4*256 float4 = 16 KiB

    adaat_params_kernel<<<BATCH, 1024, 0, stream>>>(
        para_code, W1, b1, Ws, bs, Wr, br, Wt, bt, params);

    adaat_sample_kernel<<<BATCH * CH / NP, 1024, 0, stream>>>(
        feature_map, params, (float*)d_out);
}

// Round 6
// 157.714 us; speedup vs baseline: 1.0935x; 1.0935x over previous
//
#include <hip/hip_runtime.h>
#include <math.h>

#define BATCH 4
#define CH    256   // feature channels == depth of sampled volume
#define HH    128
#define WW    128
#define PC    256   // para channels
#define PI_F  3.14159f
#define PLANE (HH * WW)   // 16384 floats = 64 KiB
#define NP    4           // planes per block

// Light barrier: only drains LDS ops (lgkmcnt). Unlike __syncthreads(), does
// NOT wait vmcnt(0) — global loads/stores stay in flight across it. Safe here:
// cross-wave hazards are LDS-only (double buffer removes WAR on plane bufs).
__device__ __forceinline__ void barrier_lds() {
    asm volatile("s_waitcnt lgkmcnt(0)\n\ts_barrier" ::: "memory");
}

struct Stage { float4 a[4]; float4 b[4]; };

__device__ __forceinline__ Stage stage_load(const float* __restrict__ pl0,
                                            const float* __restrict__ pl1, int t) {
    Stage s;
#pragma unroll
    for (int j = 0; j < 4; ++j) {
        const int f = 4 * (t + 1024 * j);
        s.a[j] = *(const float4*)(pl0 + f);
        s.b[j] = *(const float4*)(pl1 + f);
    }
    return s;
}

__device__ __forceinline__ void stage_store(float* __restrict__ buf, const Stage& s,
                                            float wz0, float wz1, int t) {
#pragma unroll
    for (int j = 0; j < 4; ++j) {
        const int f = 4 * (t + 1024 * j);
        const int y = f >> 7, x = f & (WW - 1);
        float4 c;
        c.x = fmaf(wz0, s.a[j].x, wz1 * s.b[j].x);
        c.y = fmaf(wz0, s.a[j].y, wz1 * s.b[j].y);
        c.z = fmaf(wz0, s.a[j].z, wz1 * s.b[j].z);
        c.w = fmaf(wz0, s.a[j].w, wz1 * s.b[j].w);
        *(float4*)&buf[y * WW + (x ^ ((y & 3) << 3))] = c;
    }
}

__device__ __forceinline__ void gather_plane(const float* __restrict__ buf,
                                             const float4 P,
                                             float* __restrict__ outp,
                                             const float yf, const int xi) {
    const float cA = P.x, cB = P.y;
    const float Dx = fmaf(-P.y, yf, P.z);   // y-terms hoisted out of the k-loop
    const float Dy = fmaf( P.x, yf, P.w);
#pragma unroll 2
    for (int k = 0; k < 16; ++k) {
        const float xf  = (float)(k * 8 + xi);
        const float ixf = fmaf(cA, xf, Dx);
        const float iyf = fmaf(cB, xf, Dy);
        const float x0f = floorf(ixf);
        const float y0f = floorf(iyf);
        const float fx  = ixf - x0f;
        const float fy  = iyf - y0f;
        const float mx0 = (x0f >= 0.0f  && x0f < 128.0f) ? (1.0f - fx) : 0.0f;
        const float mx1 = (x0f >= -1.0f && x0f < 127.0f) ? fx          : 0.0f;
        const float my0 = (y0f >= 0.0f  && y0f < 128.0f) ? (1.0f - fy) : 0.0f;
        const float my1 = (y0f >= -1.0f && y0f < 127.0f) ? fy          : 0.0f;

        const int x0i = (int)x0f, y0i = (int)y0f;
        const int xc0 = min(max(x0i,     0), WW - 1);
        const int xc1 = min(max(x0i + 1, 0), WW - 1);
        const int yc0 = min(max(y0i,     0), HH - 1);
        const int yc1 = min(max(y0i + 1, 0), HH - 1);

        const int r0 = yc0 * WW, r1 = yc1 * WW;
        const int s0 = (yc0 & 3) << 3, s1 = (yc1 & 3) << 3;
        const float v00 = buf[r0 + (xc0 ^ s0)];
        const float v01 = buf[r0 + (xc1 ^ s0)];
        const float v10 = buf[r1 + (xc0 ^ s1)];
        const float v11 = buf[r1 + (xc1 ^ s1)];

        outp[k * 8 + xi] = my0 * (mx0 * v00 + mx1 * v01)
                         + my1 * (mx0 * v10 + mx1 * v11);
    }
}

// ---------------------------------------------------------------------------
// One launch, 256 blocks x 1024 threads, NP=4 planes/block.
//  - plane-0 staging loads issued FIRST; params GEMV/heads run while they are
//    in flight (light barriers don't drain vmcnt, so loads stay outstanding)
//  - GEMV reduce scratch aliases plane buffer 1 (dead until iter 1's store)
//  - steady state: load(i+1) -> gather(i) -> combine/store(i+1) -> barrier_lds
// ---------------------------------------------------------------------------
__global__ __launch_bounds__(1024, 4)
void adaat_fused_kernel(const float* __restrict__ fm,
                        const float* __restrict__ pc,
                        const float* __restrict__ W1, const float* __restrict__ b1,
                        const float* __restrict__ Ws, const float* __restrict__ bs,
                        const float* __restrict__ Wr, const float* __restrict__ br,
                        const float* __restrict__ Wt, const float* __restrict__ bt,
                        float* __restrict__ out) {
    __shared__ float  buf[2][PLANE];    // 128 KiB double buffer
    __shared__ float  p_sh[PC];
    __shared__ float  sh_head[16];
    __shared__ float4 sh_par[NP];

    const int t   = threadIdx.x;
    const int bc0 = blockIdx.x * NP;    // NP | 256 so no batch straddle
    const int b   = bc0 >> 8;

    // block-uniform staging constants (scalarized)
    const float* base = fm + (size_t)b * (CH * PLANE);
    const float* pl0[NP]; const float* pl1[NP];
    float w0[NP], w1[NP];
#pragma unroll
    for (int i = 0; i < NP; ++i) {
        const int   c  = (bc0 + i) & (CH - 1);
        const float iz = (256.0f / 255.0f) * (float)c - 0.5f;
        const float zf = floorf(iz);
        const float fz = iz - zf;
        const int   z0 = (int)zf;
        w0[i]  = (z0 >= 0)     ? (1.0f - fz) : 0.0f;
        w1[i]  = (z0 + 1 < CH) ? fz          : 0.0f;
        pl0[i] = base + (size_t)max(z0, 0)          * PLANE;
        pl1[i] = base + (size_t)min(z0 + 1, CH - 1) * PLANE;
    }

    // ---- 1) issue plane-0 staging loads (stay in flight through params) ----
    Stage s = stage_load(pl0[0], pl1[0], t);

    // ---- 2) p = relu(pc @ W1 + b1); reduce scratch aliased on buf[1] ----
    {
        float* red = &buf[1][0];
        const int jj = t & 255, kk = t >> 8;
        const float* pcb = pc + b * PC + kk * 64;
        const float* w   = W1 + (kk * 64) * PC + jj;
        float acc = 0.0f;
#pragma unroll 8
        for (int i = 0; i < 64; ++i)
            acc = fmaf(pcb[i], w[i * PC], acc);
        red[t] = acc;
        barrier_lds();
        if (t < 256)
            p_sh[t] = fmaxf(red[t] + red[256 + t] + red[512 + t] + red[768 + t] + b1[t], 0.0f);
        barrier_lds();
    }

    // ---- 3) head dots: wave wv -> channel q = wv>>2, head wv&3 ----
    const int wv = t >> 6, l = t & 63;
    {
        const int q  = wv >> 2;
        const int h  = wv & 3;
        const int cq = (bc0 + q) & (CH - 1);
        const float* wp; int stride;
        if      (h == 0) { wp = Ws + cq;                stride = PC;     }
        else if (h == 1) { wp = Wr + cq;                stride = PC;     }
        else             { wp = Wt + 2 * cq + (h == 3); stride = 2 * PC; }
        float dot = 0.0f;
#pragma unroll
        for (int m = 0; m < 4; ++m) {
            const int k = l + 64 * m;
            dot = fmaf(p_sh[k], wp[(size_t)k * stride], dot);
        }
#pragma unroll
        for (int off = 32; off >= 1; off >>= 1)
            dot += __shfl_xor(dot, off, 64);
        if (l == 0) sh_head[wv] = dot;
    }
    barrier_lds();

    // ---- 4) transcendentals -> fused pixel-space affine constants ----
    if (t < NP) {
        const int cq = (bc0 + t) & (CH - 1);
        const float s2  = 2.0f / (1.0f + expf(-(sh_head[4 * t] + bs[cq])));
        const float ang = tanhf(sh_head[4 * t + 1] + br[cq]) * PI_F;
        float sa, ca;
        sincosf(ang, &sa, &ca);
        const float A  = s2 * ca, B = s2 * sa;
        const float Tx = tanhf(sh_head[4 * t + 2] + bt[2 * cq]);
        const float Ty = tanhf(sh_head[4 * t + 3] + bt[2 * cq + 1]);
        sh_par[t] = make_float4(A * (128.0f / 127.0f),
                                B * (128.0f / 127.0f),
                                64.0f * (Tx - A + B) + 63.5f,
                                64.0f * (Ty - A - B) + 63.5f);
    }

    // ---- 5) store plane 0 (combine waits on its own loads only) ----
    stage_store(&buf[0][0], s, w0[0], w1[0], t);
    barrier_lds();

    // ---- 6) pipeline over planes ----
    const int   xi = l & 7;                 // wave = 8x8 pixel tile
    const int   yj = wv * 8 + (l >> 3);
    const float yf = (float)yj;

#pragma unroll
    for (int i = 1; i < NP; ++i) {
        s = stage_load(pl0[i], pl1[i], t);  // in flight during gather
        gather_plane(&buf[(i - 1) & 1][0], sh_par[i - 1],
                     out + (size_t)(bc0 + i - 1) * PLANE + yj * WW, yf, xi);
        stage_store(&buf[i & 1][0], s, w0[i], w1[i], t);
        barrier_lds();
    }
    gather_plane(&buf[(NP - 1) & 1][0], sh_par[NP - 1],
                 out + (size_t)(bc0 + NP - 1) * PLANE + yj * WW, yf, xi);
}

// ---------------------------------------------------------------------------
extern "C" void kernel_launch(void* const* d_in, const int* in_sizes, int n_in,
                              void* d_out, int out_size, void* d_ws, size_t ws_size,
                              hipStream_t stream) {
    const float* feature_map = (const float*)d_in[0];  // [4,256,128,128]
    const float* para_code   = (const float*)d_in[1];  // [4,256]
    const float* W1 = (const float*)d_in[2];
    const float* b1 = (const float*)d_in[3];
    const float* Ws = (const float*)d_in[4];
    const float* bs = (const float*)d_in[5];
    const float* Wr = (const float*)d_in[6];
    const float* br = (const float*)d_in[7];
    const float* Wt = (const float*)d_in[8];
    const float* bt = (const float*)d_in[9];

    adaat_fused_kernel<<<BATCH * CH / NP, 1024, 0, stream>>>(
        feature_map, para_code, W1, b1, Ws, bs, Wr, br, Wt, bt, (float*)d_out);
}

// Round 7
// 150.850 us; speedup vs baseline: 1.1433x; 1.0455x over previous
//
#include <hip/hip_runtime.h>
#include <math.h>

#define BATCH 4
#define CH    256   // feature channels == depth of sampled volume
#define HH    128
#define WW    128
#define PC    256   // para channels
#define PI_F  3.14159f
#define PLANE (HH * WW)   // 16384 floats
#define NP    4           // planes per block

// Padded LDS plane: rows -1..129 (index y+1 in [0,130]), cols -1..132.
// Stride 134 words: 134 mod 32 = 6 -> any linear lane-walk (row, col,
// diagonal, scaled) hits >=16 banks => <=2-way conflict = free (m136).
// Border + padding cells hold 0.0f, zeroed once at kernel start: OOB
// sampling reads stored zeros => padding_mode='zeros' with NO mask VALU.
#define PSTRIDE 134
#define PROWS   131
#define BUFSZ   (PROWS * PSTRIDE)   // 17554 words = 70216 B per buffer

// Light barrier: drains LDS ops only (lgkmcnt), NOT vmcnt — global loads and
// output stores stay in flight across it. Cross-wave hazards here are
// LDS-only (double buffer removes WAR on plane buffers).
__device__ __forceinline__ void barrier_lds() {
    asm volatile("s_waitcnt lgkmcnt(0)\n\ts_barrier" ::: "memory");
}

struct Stage { float4 a[4]; float4 b[4]; };

__device__ __forceinline__ Stage stage_load(const float* __restrict__ pl0,
                                            const float* __restrict__ pl1, int t) {
    Stage s;
#pragma unroll
    for (int j = 0; j < 4; ++j) {
        const int f = 4 * (t + 1024 * j);
        s.a[j] = *(const float4*)(pl0 + f);
        s.b[j] = *(const float4*)(pl1 + f);
    }
    return s;
}

// z-combine + scatter into padded layout (interior cells only; border cells
// remain zero). 4 consecutive floats -> compiler merges to ds_write2_b32.
__device__ __forceinline__ void stage_store_pad(float* __restrict__ buf, const Stage& s,
                                                float wz0, float wz1, int t) {
#pragma unroll
    for (int j = 0; j < 4; ++j) {
        const int f = 4 * (t + 1024 * j);
        const int y = f >> 7, x = f & (WW - 1);
        float* p = &buf[(y + 1) * PSTRIDE + (x + 1)];
        p[0] = fmaf(wz0, s.a[j].x, wz1 * s.b[j].x);
        p[1] = fmaf(wz0, s.a[j].y, wz1 * s.b[j].y);
        p[2] = fmaf(wz0, s.a[j].z, wz1 * s.b[j].z);
        p[3] = fmaf(wz0, s.a[j].w, wz1 * s.b[j].w);
    }
}

// Bilinear gather from the padded plane. P.z/P.w carry the +1 border bias.
// Clamp coord into [0, 129.99]: far-OOB pixels land entirely on zero cells;
// edge pixels get the exact zero-padded weights (bilinear is continuous, so
// the clamp point fx=0 / border-zero reads reproduce F.grid_sample exactly).
__device__ __forceinline__ void gather_plane(const float* __restrict__ buf,
                                             const float4 P,
                                             float* __restrict__ outp,
                                             const float yf, const int xi) {
    const float cA  = P.x, cB = P.y;
    float ixp = fmaf(cA, (float)xi, fmaf(-cB, yf, P.z));
    float iyp = fmaf(cB, (float)xi, fmaf( cA, yf, P.w));
    const float dx8 = 8.0f * cA, dy8 = 8.0f * cB;   // exact (x8)
#pragma unroll 4
    for (int k = 0; k < 16; ++k) {
        const float xc  = fminf(fmaxf(ixp, 0.0f), 129.99f);
        const float yc  = fminf(fmaxf(iyp, 0.0f), 129.99f);
        const float x0f = floorf(xc), y0f = floorf(yc);
        const float fx  = xc - x0f,   fy  = yc - y0f;
        const int   a   = (int)y0f * PSTRIDE + (int)x0f;
        const float v00 = buf[a],           v01 = buf[a + 1];           // ds_read2
        const float v10 = buf[a + PSTRIDE], v11 = buf[a + PSTRIDE + 1]; // ds_read2
        const float h0  = fmaf(fx, v01 - v00, v00);
        const float h1  = fmaf(fx, v11 - v10, v10);
        outp[k * 8 + xi] = fmaf(fy, h1 - h0, h0);
        ixp += dx8; iyp += dy8;
    }
}

// ---------------------------------------------------------------------------
// One launch, 256 blocks x 1024 threads, NP=4 planes/block, double-buffered
// padded LDS planes. Plane-0 global loads issue first and stay in flight
// through the params phase (light barriers never drain vmcnt).
// ---------------------------------------------------------------------------
__global__ __launch_bounds__(1024, 4)
void adaat_fused_kernel(const float* __restrict__ fm,
                        const float* __restrict__ pc,
                        const float* __restrict__ W1, const float* __restrict__ b1,
                        const float* __restrict__ Ws, const float* __restrict__ bs,
                        const float* __restrict__ Wr, const float* __restrict__ br,
                        const float* __restrict__ Wt, const float* __restrict__ bt,
                        float* __restrict__ out) {
    __shared__ float  lds[2 * BUFSZ];   // 140.4 KiB padded double buffer
    __shared__ float  red[1024];        // GEMV reduce scratch (4 KiB)
    __shared__ float  p_sh[PC];
    __shared__ float  sh_head[16];
    __shared__ float4 sh_par[NP];

    const int t   = threadIdx.x;
    const int bc0 = blockIdx.x * NP;    // NP | 256 so no batch straddle
    const int b   = bc0 >> 8;

    // block-uniform staging constants (scalarized)
    const float* base = fm + (size_t)b * (CH * PLANE);
    const float* pl0[NP]; const float* pl1[NP];
    float w0[NP], w1[NP];
#pragma unroll
    for (int i = 0; i < NP; ++i) {
        const int   c  = (bc0 + i) & (CH - 1);
        const float iz = (256.0f / 255.0f) * (float)c - 0.5f;
        const float zf = floorf(iz);
        const float fz = iz - zf;
        const int   z0 = (int)zf;
        w0[i]  = (z0 >= 0)     ? (1.0f - fz) : 0.0f;
        w1[i]  = (z0 + 1 < CH) ? fz          : 0.0f;
        pl0[i] = base + (size_t)max(z0, 0)          * PLANE;
        pl1[i] = base + (size_t)min(z0 + 1, CH - 1) * PLANE;
    }

    // ---- 1) plane-0 staging loads in flight through all of params ----
    Stage s = stage_load(pl0[0], pl1[0], t);

    // ---- 2) zero both padded buffers (borders must read 0.0f) ----
#pragma unroll
    for (int i = 0; i < 35; ++i) {
        const int idx = t + 1024 * i;
        if (idx < 2 * BUFSZ) lds[idx] = 0.0f;
    }

    // ---- 3) p = relu(pc @ W1 + b1), 4-way k-split ----
    {
        const int jj = t & 255, kk = t >> 8;
        const float* pcb = pc + b * PC + kk * 64;
        const float* w   = W1 + (kk * 64) * PC + jj;
        float acc = 0.0f;
#pragma unroll 8
        for (int i = 0; i < 64; ++i)
            acc = fmaf(pcb[i], w[i * PC], acc);
        red[t] = acc;
    }
    barrier_lds();
    if (t < 256)
        p_sh[t] = fmaxf(red[t] + red[256 + t] + red[512 + t] + red[768 + t] + b1[t], 0.0f);
    barrier_lds();   // p_sh visible; zeroing drained

    // ---- 4) store plane 0 (waits only its own vmcnt); overlaps heads ----
    stage_store_pad(&lds[0], s, w0[0], w1[0], t);

    // ---- 5) head dots: wave wv -> channel q = wv>>2, head wv&3 ----
    const int wv = t >> 6, l = t & 63;
    {
        const int q  = wv >> 2;
        const int h  = wv & 3;
        const int cq = (bc0 + q) & (CH - 1);
        const float* wp; int stride;
        if      (h == 0) { wp = Ws + cq;                stride = PC;     }
        else if (h == 1) { wp = Wr + cq;                stride = PC;     }
        else             { wp = Wt + 2 * cq + (h == 3); stride = 2 * PC; }
        float dot = 0.0f;
#pragma unroll
        for (int m = 0; m < 4; ++m) {
            const int k = l + 64 * m;
            dot = fmaf(p_sh[k], wp[(size_t)k * stride], dot);
        }
#pragma unroll
        for (int off = 32; off >= 1; off >>= 1)
            dot += __shfl_xor(dot, off, 64);
        if (l == 0) sh_head[wv] = dot;
    }
    barrier_lds();

    // ---- 6) transcendentals -> fused padded-pixel-space constants ----
    if (t < NP) {
        const int cq = (bc0 + t) & (CH - 1);
        const float s2  = 2.0f / (1.0f + expf(-(sh_head[4 * t] + bs[cq])));
        const float ang = tanhf(sh_head[4 * t + 1] + br[cq]) * PI_F;
        float sa, ca;
        sincosf(ang, &sa, &ca);
        const float A  = s2 * ca, B = s2 * sa;
        const float Tx = tanhf(sh_head[4 * t + 2] + bt[2 * cq]);
        const float Ty = tanhf(sh_head[4 * t + 3] + bt[2 * cq + 1]);
        sh_par[t] = make_float4(A * (128.0f / 127.0f),
                                B * (128.0f / 127.0f),
                                64.0f * (Tx - A + B) + 64.5f,   // +1 border bias
                                64.0f * (Ty - A - B) + 64.5f);
    }
    barrier_lds();   // sh_par + plane-0 stores visible

    // ---- 7) pipeline over planes ----
    const int   xi = l & 7;                 // wave = 8x8 pixel tile
    const int   yj = wv * 8 + (l >> 3);
    const float yf = (float)yj;

#pragma unroll
    for (int i = 1; i < NP; ++i) {
        s = stage_load(pl0[i], pl1[i], t);  // in flight during gather
        gather_plane(&lds[((i - 1) & 1) * BUFSZ], sh_par[i - 1],
                     out + (size_t)(bc0 + i - 1) * PLANE + yj * WW, yf, xi);
        stage_store_pad(&lds[(i & 1) * BUFSZ], s, w0[i], w1[i], t);
        barrier_lds();
    }
    gather_plane(&lds[((NP - 1) & 1) * BUFSZ], sh_par[NP - 1],
                 out + (size_t)(bc0 + NP - 1) * PLANE + yj * WW, yf, xi);
}

// ---------------------------------------------------------------------------
extern "C" void kernel_launch(void* const* d_in, const int* in_sizes, int n_in,
                              void* d_out, int out_size, void* d_ws, size_t ws_size,
                              hipStream_t stream) {
    const float* feature_map = (const float*)d_in[0];  // [4,256,128,128]
    const float* para_code   = (const float*)d_in[1];  // [4,256]
    const float* W1 = (const float*)d_in[2];
    const float* b1 = (const float*)d_in[3];
    const float* Ws = (const float*)d_in[4];
    const float* bs = (const float*)d_in[5];
    const float* Wr = (const float*)d_in[6];
    const float* br = (const float*)d_in[7];
    const float* Wt = (const float*)d_in[8];
    const float* bt = (const float*)d_in[9];

    adaat_fused_kernel<<<BATCH * CH / NP, 1024, 0, stream>>>(
        feature_map, para_code, W1, b1, Ws, bs, Wr, br, Wt, bt, (float*)d_out);
}